// Round 2
// baseline (10973.606 us; speedup 1.0000x reference)
//
#include <hip/hip_runtime.h>
#include <hip/hip_bf16.h>
#include <cmath>

#define BATCH 8
#define CIN 64
#define COUT 128
#define NPTS 16384
#define RES 32
#define R3 32768
#define NGROUP 8
#define GSIZE 16

typedef __hip_bfloat16 bf16;

__device__ inline float ldf(const float* p, size_t i) { return p[i]; }
__device__ inline float ldf(const bf16* p, size_t i) { return __bfloat162float(p[i]); }
__device__ inline void stf(float* p, size_t i, float v) { p[i] = v; }
__device__ inline void stf(bf16* p, size_t i, float v) { p[i] = __float2bfloat16(v); }

// ---------------- coord stats: per-batch mean(3) + 1/(2*maxnorm) ----------------
__global__ __launch_bounds__(256) void coord_stats_k(const float* __restrict__ coords,
                                                     float* __restrict__ bstats) {
    int b = blockIdx.x;
    int t = threadIdx.x;
    __shared__ float red[256];
    __shared__ float means[3];
    for (int c = 0; c < 3; ++c) {
        float acc = 0.f;
        const float* p = coords + ((size_t)b * 3 + c) * NPTS;
        for (int n = t; n < NPTS; n += 256) acc += p[n];
        red[t] = acc; __syncthreads();
        for (int s = 128; s > 0; s >>= 1) { if (t < s) red[t] += red[t + s]; __syncthreads(); }
        if (t == 0) means[c] = red[0] * (1.f / NPTS);
        __syncthreads();
    }
    float m0 = means[0], m1 = means[1], m2 = means[2];
    const float* px = coords + ((size_t)b * 3 + 0) * NPTS;
    const float* py = coords + ((size_t)b * 3 + 1) * NPTS;
    const float* pz = coords + ((size_t)b * 3 + 2) * NPTS;
    float mx = 0.f;
    for (int n = t; n < NPTS; n += 256) {
        float dx = px[n] - m0, dy = py[n] - m1, dz = pz[n] - m2;
        mx = fmaxf(mx, sqrtf(dx * dx + dy * dy + dz * dz));
    }
    red[t] = mx; __syncthreads();
    for (int s = 128; s > 0; s >>= 1) { if (t < s) red[t] = fmaxf(red[t], red[t + s]); __syncthreads(); }
    if (t == 0) {
        bstats[b * 4 + 0] = m0; bstats[b * 4 + 1] = m1; bstats[b * 4 + 2] = m2;
        bstats[b * 4 + 3] = 1.f / (2.f * red[0]);
    }
}

// ---------------- voxelize: write nc, scatter-add sums/cnts ----------------
__global__ __launch_bounds__(256) void voxelize_k(const float* __restrict__ coords,
                                                  const float* __restrict__ feats,
                                                  const float* __restrict__ bstats,
                                                  float* __restrict__ nc,
                                                  float* __restrict__ sums,
                                                  float* __restrict__ cnts) {
    int g = blockIdx.x * 256 + threadIdx.x;
    int b = g / NPTS, n = g % NPTS;
    float m0 = bstats[b * 4 + 0], m1 = bstats[b * 4 + 1], m2 = bstats[b * 4 + 2];
    float sc = bstats[b * 4 + 3];
    float x = coords[((size_t)b * 3 + 0) * NPTS + n];
    float y = coords[((size_t)b * 3 + 1) * NPTS + n];
    float z = coords[((size_t)b * 3 + 2) * NPTS + n];
    float ncx = fminf(fmaxf(((x - m0) * sc + 0.5f) * (float)RES, 0.f), RES - 1.f);
    float ncy = fminf(fmaxf(((y - m1) * sc + 0.5f) * (float)RES, 0.f), RES - 1.f);
    float ncz = fminf(fmaxf(((z - m2) * sc + 0.5f) * (float)RES, 0.f), RES - 1.f);
    nc[((size_t)b * 3 + 0) * NPTS + n] = ncx;
    nc[((size_t)b * 3 + 1) * NPTS + n] = ncy;
    nc[((size_t)b * 3 + 2) * NPTS + n] = ncz;
    int ix = min(max((int)rintf(ncx), 0), RES - 1);  // rintf = round-half-even = jnp.round
    int iy = min(max((int)rintf(ncy), 0), RES - 1);
    int iz = min(max((int)rintf(ncz), 0), RES - 1);
    int flat = (ix * RES + iy) * RES + iz;
    atomicAdd(&cnts[(size_t)b * R3 + flat], 1.f);
    size_t sbase = ((size_t)b * CIN) * R3 + flat;
    size_t fbase = ((size_t)b * CIN) * NPTS + n;
    for (int c = 0; c < CIN; ++c)
        atomicAdd(&sums[sbase + (size_t)c * R3], feats[fbase + (size_t)c * NPTS]);
}

// ---------------- finalize: sums -> mean ----------------
__global__ __launch_bounds__(256) void finalize_vox_k(float* __restrict__ vox,
                                                      const float* __restrict__ cnts) {
    int g = blockIdx.x * 256 + threadIdx.x;  // over BATCH*R3
    int b = g / R3, p = g % R3;
    float inv = 1.f / fmaxf(cnts[g], 1.f);
    size_t base = ((size_t)b * CIN) * R3 + p;
    for (int c = 0; c < CIN; ++c) vox[base + (size_t)c * R3] *= inv;
}

// ---------------- direct conv3d 3x3x3, SAME, Cout=128, bf16 output ----------------
// block = (b, d, h-pair). wave = 32 w x 2 h -> co-group (t>>6) is wave-uniform
// (forced scalar via readfirstlane) so weight loads become s_load.
template <int CIN_T, typename TIN>
__global__ __launch_bounds__(256) void conv3d_k(const TIN* __restrict__ x,
                                                const float* __restrict__ wgt,
                                                const float* __restrict__ bias,
                                                bf16* __restrict__ y) {
    int blk = blockIdx.x;
    int h2 = blk & 15;
    int d = (blk >> 4) & 31;
    int b = blk >> 9;
    int t = threadIdx.x;
    int lane = t & 63;
    int wp = lane & 31;   // w position
    int hs = lane >> 5;   // 0/1: which h row
    int cog = __builtin_amdgcn_readfirstlane((int)(t >> 6));  // 0..3, wave-uniform

    __shared__ float xs[32][12][34];  // ci-chunk x (dd 0..2, hh 0..3) x padded row; 52 KB
    float acc[32];
#pragma unroll
    for (int i = 0; i < 32; ++i) acc[i] = 0.f;

    for (int cc = 0; cc < CIN_T; cc += 32) {
        __syncthreads();
        for (int e = t; e < 32 * 12 * 32; e += 256) {
            int ww = e & 31;
            int r = (e >> 5) % 12;
            int ci = e / 384;
            int dd = r >> 2, hh = r & 3;
            int dz = d + dd - 1;
            int hz = h2 * 2 + hh - 1;
            float v = 0.f;
            if (dz >= 0 && dz < RES && hz >= 0 && hz < RES)
                v = ldf(x, ((size_t)b * CIN_T + cc + ci) * R3 + dz * 1024 + hz * 32 + ww);
            xs[ci][r][ww + 1] = v;
        }
        for (int e = t; e < 32 * 12; e += 256) {
            int r = e % 12, ci = e / 12;
            xs[ci][r][0] = 0.f; xs[ci][r][33] = 0.f;
        }
        __syncthreads();

        for (int ci = 0; ci < 32; ++ci) {
            float xv[27];
#pragma unroll
            for (int dd = 0; dd < 3; ++dd)
#pragma unroll
                for (int dh = 0; dh < 3; ++dh)
#pragma unroll
                    for (int j = 0; j < 3; ++j)
                        xv[(dd * 3 + dh) * 3 + j] = xs[ci][dd * 4 + dh + hs][wp + j];
            const float* wrow = wgt + ((size_t)(cog * 32) * CIN_T + (cc + ci)) * 27;
#pragma unroll 4
            for (int k = 0; k < 32; ++k) {
                const float* wk = wrow + (size_t)k * CIN_T * 27;
                float a = acc[k];
#pragma unroll
                for (int q = 0; q < 27; ++q) a = fmaf(wk[q], xv[q], a);
                acc[k] = a;
            }
        }
    }
    int h = h2 * 2 + hs;
    size_t obase = ((size_t)b * COUT + cog * 32) * R3 + d * 1024 + h * 32 + wp;
#pragma unroll
    for (int k = 0; k < 32; ++k)
        y[obase + (size_t)k * R3] = __float2bfloat16(acc[k] + bias[cog * 32 + k]);
}

// ---------------- group-norm stats: one block per (b,g) ----------------
template <typename T>
__global__ __launch_bounds__(1024) void gn_stats_k(const T* __restrict__ x,
                                                   float* __restrict__ gmean,
                                                   float* __restrict__ gistd, int S) {
    int bg = blockIdx.x;  // (b*8+g); group channels contiguous: base = bg*16*S
    int t = threadIdx.x;
    const T* p = x + (size_t)bg * GSIZE * S;
    int M = GSIZE * S;
    float s = 0.f, ss = 0.f;
    for (int e = t; e < M; e += 1024) { float v = ldf(p, e); s += v; ss = fmaf(v, v, ss); }
    __shared__ float r1[1024], r2[1024];
    r1[t] = s; r2[t] = ss; __syncthreads();
    for (int st = 512; st > 0; st >>= 1) {
        if (t < st) { r1[t] += r1[t + st]; r2[t] += r2[t + st]; }
        __syncthreads();
    }
    if (t == 0) {
        float mean = r1[0] / (float)M;
        float var = fmaxf(r2[0] / (float)M - mean * mean, 0.f);
        gmean[bg] = mean;
        gistd[bg] = rsqrtf(var + 1e-5f);
    }
}

// ---------------- GN apply + swish, in place; S power of two ----------------
template <typename T>
__global__ __launch_bounds__(256) void gn_apply_swish_k(T* __restrict__ x,
                                                        const float* __restrict__ gmean,
                                                        const float* __restrict__ gistd,
                                                        const float* __restrict__ gamma,
                                                        const float* __restrict__ beta,
                                                        int logS) {
    unsigned int i = blockIdx.x * 256u + threadIdx.x;  // over B*128*S (<2^31)
    int c = (int)((i >> logS) & (COUT - 1));
    int bg = (int)(i >> (logS + 4));
    float v = ldf(x, i);
    float xn = (v - gmean[bg]) * gistd[bg];
    float yv = fmaf(xn, gamma[c], beta[c]);
    stf(x, i, yv / (1.f + expf(-yv)));
}

// ---------------- point branch GEMM: pf = wp @ features + bp (into d_out) ----------------
__global__ __launch_bounds__(256) void point_gemm_k(const float* __restrict__ feats,
                                                    const float* __restrict__ wp,
                                                    const float* __restrict__ bp,
                                                    float* __restrict__ pf) {
    int blk = blockIdx.x;
    int b = blk / (NPTS / 256);
    int n = (blk % (NPTS / 256)) * 256 + threadIdx.x;
    float f[CIN];
    const float* fp = feats + ((size_t)b * CIN) * NPTS + n;
#pragma unroll
    for (int ci = 0; ci < CIN; ++ci) f[ci] = fp[(size_t)ci * NPTS];
    for (int c0 = 0; c0 < COUT; c0 += 8) {
        float a[8];
#pragma unroll
        for (int k = 0; k < 8; ++k) a[k] = bp[c0 + k];
#pragma unroll
        for (int ci = 0; ci < CIN; ++ci) {
            float fv = f[ci];
#pragma unroll
            for (int k = 0; k < 8; ++k) a[k] = fmaf(wp[(size_t)(c0 + k) * CIN + ci], fv, a[k]);
        }
        size_t ob = ((size_t)b * COUT + c0) * NPTS + n;
#pragma unroll
        for (int k = 0; k < 8; ++k) pf[ob + (size_t)k * NPTS] = a[k];
    }
}

// ---------------- trilinear devox + add point branch (in place on d_out) ----------------
__global__ __launch_bounds__(256) void fuse_k(const bf16* __restrict__ vox,
                                              const float* __restrict__ nc,
                                              float* __restrict__ out) {
    int g = blockIdx.x * 256 + threadIdx.x;  // over BATCH*NPTS
    int b = g / NPTS, n = g % NPTS;
    const float CMAX = (float)(RES - 1) - 1e-6f;
    float cx = fminf(nc[((size_t)b * 3 + 0) * NPTS + n], CMAX);
    float cy = fminf(nc[((size_t)b * 3 + 1) * NPTS + n], CMAX);
    float cz = fminf(nc[((size_t)b * 3 + 2) * NPTS + n], CMAX);
    int ix0 = (int)cx, iy0 = (int)cy, iz0 = (int)cz;  // floor (nonneg)
    float fx = cx - ix0, fy = cy - iy0, fz = cz - iz0;
    int ix1 = min(ix0 + 1, RES - 1), iy1 = min(iy0 + 1, RES - 1), iz1 = min(iz0 + 1, RES - 1);
    float gx0 = 1.f - fx, gy0 = 1.f - fy, gz0 = 1.f - fz;
    float w000 = gx0 * gy0 * gz0, w001 = gx0 * gy0 * fz;
    float w010 = gx0 * fy * gz0,  w011 = gx0 * fy * fz;
    float w100 = fx * gy0 * gz0,  w101 = fx * gy0 * fz;
    float w110 = fx * fy * gz0,   w111 = fx * fy * fz;
    int f000 = (ix0 * RES + iy0) * RES + iz0, f001 = (ix0 * RES + iy0) * RES + iz1;
    int f010 = (ix0 * RES + iy1) * RES + iz0, f011 = (ix0 * RES + iy1) * RES + iz1;
    int f100 = (ix1 * RES + iy0) * RES + iz0, f101 = (ix1 * RES + iy0) * RES + iz1;
    int f110 = (ix1 * RES + iy1) * RES + iz0, f111 = (ix1 * RES + iy1) * RES + iz1;
    const bf16* vb = vox + ((size_t)b * COUT) * R3;
    float* ob = out + ((size_t)b * COUT) * NPTS + n;
    for (int co = 0; co < COUT; ++co) {
        const bf16* v = vb + (size_t)co * R3;
        float val = __bfloat162float(v[f000]) * w000 + __bfloat162float(v[f001]) * w001 +
                    __bfloat162float(v[f010]) * w010 + __bfloat162float(v[f011]) * w011 +
                    __bfloat162float(v[f100]) * w100 + __bfloat162float(v[f101]) * w101 +
                    __bfloat162float(v[f110]) * w110 + __bfloat162float(v[f111]) * w111;
        ob[(size_t)co * NPTS] += val;  // pf already there
    }
}

extern "C" void kernel_launch(void* const* d_in, const int* in_sizes, int n_in,
                              void* d_out, int out_size, void* d_ws, size_t ws_size,
                              hipStream_t stream) {
    const float* features = (const float*)d_in[0];
    const float* coords   = (const float*)d_in[1];
    // d_in[2] = temb, unused by reference
    const float* w1  = (const float*)d_in[3];
    const float* b1  = (const float*)d_in[4];
    const float* g1g = (const float*)d_in[5];
    const float* g1b = (const float*)d_in[6];
    const float* w2  = (const float*)d_in[7];
    const float* b2  = (const float*)d_in[8];
    const float* g2g = (const float*)d_in[9];
    const float* g2b = (const float*)d_in[10];
    const float* wp  = (const float*)d_in[11];
    const float* bp  = (const float*)d_in[12];
    const float* gpg = (const float*)d_in[13];
    const float* gpb = (const float*)d_in[14];
    float* out = (float*)d_out;

    // Workspace layout (total ~130.6 MB):
    //   regA: 64 MB  — vox fp32 (B*CIN*R3*4) -> later conv2 out bf16 (B*COUT*R3*2, same 64 MB)
    //   regB: 64 MB  — conv1 out bf16 (B*COUT*R3*2)
    //   nc:   1.5 MB, cnts: 1 MB, bstats/gmean/gistd: <1 KB
    // pf lives in d_out (64 MB) and is fused in place.
    char* ws = (char*)d_ws;
    size_t szA = (size_t)BATCH * CIN * R3 * 4;        // 64 MB
    size_t offB = szA;
    size_t offNC = offB + (size_t)BATCH * COUT * R3 * 2;   // 64MB+64MB
    size_t offCNT = offNC + (size_t)BATCH * 3 * NPTS * 4;
    size_t offBST = offCNT + (size_t)BATCH * R3 * 4;
    size_t offGM = offBST + 256;
    size_t offGI = offGM + 256;
    float* voxA   = (float*)ws;                 // fp32 vox
    bf16*  conv2o = (bf16*)ws;                  // bf16 conv2 out (overwrites vox)
    bf16*  conv1o = (bf16*)(ws + offB);
    float* ncb    = (float*)(ws + offNC);
    float* cnts   = (float*)(ws + offCNT);
    float* bstats = (float*)(ws + offBST);
    float* gmean  = (float*)(ws + offGM);
    float* gistd  = (float*)(ws + offGI);

    hipMemsetAsync(voxA, 0, szA, stream);
    hipMemsetAsync(cnts, 0, (size_t)BATCH * R3 * 4, stream);

    coord_stats_k<<<BATCH, 256, 0, stream>>>(coords, bstats);
    voxelize_k<<<BATCH * NPTS / 256, 256, 0, stream>>>(coords, features, bstats, ncb, voxA, cnts);
    finalize_vox_k<<<BATCH * R3 / 256, 256, 0, stream>>>(voxA, cnts);

    conv3d_k<CIN, float><<<BATCH * 32 * 16, 256, 0, stream>>>(voxA, w1, b1, conv1o);
    gn_stats_k<bf16><<<BATCH * NGROUP, 1024, 0, stream>>>(conv1o, gmean, gistd, R3);
    gn_apply_swish_k<bf16><<<BATCH * COUT * R3 / 256, 256, 0, stream>>>(conv1o, gmean, gistd, g1g, g1b, 15);

    conv3d_k<COUT, bf16><<<BATCH * 32 * 16, 256, 0, stream>>>(conv1o, w2, b2, conv2o);
    gn_stats_k<bf16><<<BATCH * NGROUP, 1024, 0, stream>>>(conv2o, gmean, gistd, R3);
    gn_apply_swish_k<bf16><<<BATCH * COUT * R3 / 256, 256, 0, stream>>>(conv2o, gmean, gistd, g2g, g2b, 15);

    point_gemm_k<<<BATCH * NPTS / 256, 256, 0, stream>>>(features, wp, bp, out);
    gn_stats_k<float><<<BATCH * NGROUP, 1024, 0, stream>>>(out, gmean, gistd, NPTS);
    gn_apply_swish_k<float><<<BATCH * COUT * NPTS / 256, 256, 0, stream>>>(out, gmean, gistd, gpg, gpb, 14);

    fuse_k<<<BATCH * NPTS / 256, 256, 0, stream>>>(conv2o, ncb, out);
}

// Round 3
// 1448.333 us; speedup vs baseline: 7.5767x; 7.5767x over previous
//
#include <hip/hip_runtime.h>
#include <hip/hip_bf16.h>
#include <cmath>

#define BATCH 8
#define CIN 64
#define COUT 128
#define NPTS 16384
#define RES 32
#define R3 32768
#define NGROUP 8
#define GSIZE 16

typedef __hip_bfloat16 bf16;
typedef __attribute__((ext_vector_type(8))) short short8;
typedef __attribute__((ext_vector_type(4))) float f32x4;

__device__ inline float b2f(ushort u) { union { float f; uint v; } x; x.v = ((uint)u) << 16; return x.f; }
__device__ inline ushort f2bu(float f) { __hip_bfloat16 h = __float2bfloat16(f); return *reinterpret_cast<ushort*>(&h); }
__device__ inline float ldf(const float* p, size_t i) { return p[i]; }
__device__ inline void stf(float* p, size_t i, float v) { p[i] = v; }

// ---------------- coord stats ----------------
__global__ __launch_bounds__(256) void coord_stats_k(const float* __restrict__ coords,
                                                     float* __restrict__ bstats) {
    int b = blockIdx.x;
    int t = threadIdx.x;
    __shared__ float red[256];
    __shared__ float means[3];
    for (int c = 0; c < 3; ++c) {
        float acc = 0.f;
        const float* p = coords + ((size_t)b * 3 + c) * NPTS;
        for (int n = t; n < NPTS; n += 256) acc += p[n];
        red[t] = acc; __syncthreads();
        for (int s = 128; s > 0; s >>= 1) { if (t < s) red[t] += red[t + s]; __syncthreads(); }
        if (t == 0) means[c] = red[0] * (1.f / NPTS);
        __syncthreads();
    }
    float m0 = means[0], m1 = means[1], m2 = means[2];
    const float* px = coords + ((size_t)b * 3 + 0) * NPTS;
    const float* py = coords + ((size_t)b * 3 + 1) * NPTS;
    const float* pz = coords + ((size_t)b * 3 + 2) * NPTS;
    float mx = 0.f;
    for (int n = t; n < NPTS; n += 256) {
        float dx = px[n] - m0, dy = py[n] - m1, dz = pz[n] - m2;
        mx = fmaxf(mx, sqrtf(dx * dx + dy * dy + dz * dz));
    }
    red[t] = mx; __syncthreads();
    for (int s = 128; s > 0; s >>= 1) { if (t < s) red[t] = fmaxf(red[t], red[t + s]); __syncthreads(); }
    if (t == 0) {
        bstats[b * 4 + 0] = m0; bstats[b * 4 + 1] = m1; bstats[b * 4 + 2] = m2;
        bstats[b * 4 + 3] = 1.f / (2.f * red[0]);
    }
}

// ---------------- voxelize: nc + channel-last scatter-mean sums ----------------
__global__ __launch_bounds__(256) void voxelize_k(const float* __restrict__ coords,
                                                  const float* __restrict__ feats,
                                                  const float* __restrict__ bstats,
                                                  float* __restrict__ nc,
                                                  float* __restrict__ sums,   // [b][p][64]
                                                  float* __restrict__ cnts) {
    int g = blockIdx.x * 256 + threadIdx.x;
    int b = g / NPTS, n = g % NPTS;
    float m0 = bstats[b * 4 + 0], m1 = bstats[b * 4 + 1], m2 = bstats[b * 4 + 2];
    float sc = bstats[b * 4 + 3];
    float x = coords[((size_t)b * 3 + 0) * NPTS + n];
    float y = coords[((size_t)b * 3 + 1) * NPTS + n];
    float z = coords[((size_t)b * 3 + 2) * NPTS + n];
    float ncx = fminf(fmaxf(((x - m0) * sc + 0.5f) * (float)RES, 0.f), RES - 1.f);
    float ncy = fminf(fmaxf(((y - m1) * sc + 0.5f) * (float)RES, 0.f), RES - 1.f);
    float ncz = fminf(fmaxf(((z - m2) * sc + 0.5f) * (float)RES, 0.f), RES - 1.f);
    nc[((size_t)b * 3 + 0) * NPTS + n] = ncx;
    nc[((size_t)b * 3 + 1) * NPTS + n] = ncy;
    nc[((size_t)b * 3 + 2) * NPTS + n] = ncz;
    int ix = min(max((int)rintf(ncx), 0), RES - 1);
    int iy = min(max((int)rintf(ncy), 0), RES - 1);
    int iz = min(max((int)rintf(ncz), 0), RES - 1);
    int flat = (ix * RES + iy) * RES + iz;
    atomicAdd(&cnts[(size_t)b * R3 + flat], 1.f);
    float* sb = sums + ((size_t)b * R3 + flat) * CIN;
    const float* fb = feats + ((size_t)b * CIN) * NPTS + n;
    for (int c = 0; c < CIN; ++c)
        atomicAdd(&sb[c], fb[(size_t)c * NPTS]);
}

// ---------------- finalize: sums/cnt -> bf16 channel-last vox ----------------
__global__ __launch_bounds__(256) void finalize_convert_k(const float* __restrict__ sums,
                                                          const float* __restrict__ cnts,
                                                          bf16* __restrict__ voxCL) {
    int u = blockIdx.x * 256 + threadIdx.x;  // (b, p, ci-octet) : 8*32768*8
    int ci8 = u & 7;
    int p = (u >> 3) & (R3 - 1);
    int b = u >> 18;
    float inv = 1.f / fmaxf(cnts[(size_t)b * R3 + p], 1.f);
    const float* s = sums + ((size_t)b * R3 + p) * CIN + ci8 * 8;
    ushort o[8];
#pragma unroll
    for (int j = 0; j < 8; ++j) o[j] = f2bu(s[j] * inv);
    *(short8*)(voxCL + ((size_t)b * R3 + p) * CIN + ci8 * 8) = *(short8*)o;
}

// ---------------- weight reorder: [co][ci][27] fp32 -> [t][c32][co][kb][8] bf16 ----------------
template <int CIN_T>
__global__ __launch_bounds__(256) void wreorder_k(const float* __restrict__ w,
                                                  bf16* __restrict__ wf) {
    const int NC = CIN_T / 32;
    int u = blockIdx.x * 256 + threadIdx.x;  // (t, c32, co, kb)
    if (u >= 27 * NC * 128 * 4) return;
    int kb = u & 3;
    int co = (u >> 2) & 127;
    int c32 = (u >> 9) % NC;
    int t = u / (512 * NC);
    int cibase = c32 * 32 + kb * 8;
    ushort o[8];
#pragma unroll
    for (int j = 0; j < 8; ++j)
        o[j] = f2bu(w[((size_t)co * CIN_T + cibase + j) * 27 + t]);
    *(short8*)(wf + (size_t)u * 8) = *(short8*)o;
}

// ---------------- implicit-GEMM conv3d 3x3x3 via MFMA bf16 ----------------
// grid: (b, d, hq) ; block 512 = 8 waves (4 co-groups x 2 spatial-groups)
// out tile: 128 co x (4 h-rows x 32 w) = 128 sp, channel-last bf16
template <int CIN_T>
__global__ __launch_bounds__(512, 2) void conv3d_mfma_k(const bf16* __restrict__ x,  // [b][p][CIN_T]
                                                        const bf16* __restrict__ wf, // [27][NC][128][4][8]
                                                        const float* __restrict__ bias,
                                                        bf16* __restrict__ y) {      // [b][p][128]
    constexpr int NC = CIN_T / 32;
    int blk = blockIdx.x;
    int hq = blk & 7;
    int d = (blk >> 3) & 31;
    int b = blk >> 8;
    int t = threadIdx.x;
    int lane = t & 63;
    int wid = t >> 6;
    int cog = wid >> 1;  // 0..3
    int sg = wid & 1;    // 0..1
    int lr = lane & 15;
    int kb = lane >> 4;  // 0..3

    // LDS tile: pos(dd 0..2, hh 0..5, ww 0..33), 80B per pos (4x16B used + 16B pad)
    __shared__ __align__(16) char xs[3 * 6 * 34 * 80];

    f32x4 acc[2][4];
#pragma unroll
    for (int r = 0; r < 2; ++r)
#pragma unroll
        for (int j = 0; j < 4; ++j) acc[r][j] = (f32x4){0.f, 0.f, 0.f, 0.f};

    // per-lane B base byte offsets (one per spatial tile j)
    int bbase[4];
#pragma unroll
    for (int j = 0; j < 4; ++j) {
        int sp = sg * 64 + j * 16 + lr;
        int hl = sp >> 5, wl = sp & 31;
        bbase[j] = (hl * 34 + wl) * 80 + kb * 16;
    }

    for (int cc = 0; cc < NC; ++cc) {
        __syncthreads();
        // stage: 612 positions x 4 slots
        for (int e = t; e < 612 * 4; e += 512) {
            int ekb = e & 3;
            int pos = e >> 2;
            int ww = pos % 34;
            int hh = (pos / 34) % 6;
            int dd = pos / 204;
            int dz = d + dd - 1;
            int hz = hq * 4 + hh - 1;
            int wz = ww - 1;
            short8 v = {0, 0, 0, 0, 0, 0, 0, 0};
            if (dz >= 0 && dz < RES && hz >= 0 && hz < RES && wz >= 0 && wz < RES)
                v = *(const short8*)(x + ((size_t)b * R3 + dz * 1024 + hz * 32 + wz) * CIN_T + cc * 32 + ekb * 8);
            *(short8*)(xs + pos * 80 + ekb * 16) = v;
        }
        __syncthreads();

        const short8* wfp = (const short8*)wf;
        size_t abase = ((size_t)cc * 128 + cog * 32 + lr) * 4 + kb;
#pragma unroll
        for (int dd = 0; dd < 3; ++dd)
#pragma unroll
            for (int dh = 0; dh < 3; ++dh)
#pragma unroll
                for (int dw = 0; dw < 3; ++dw) {
                    int tap = (dd * 3 + dh) * 3 + dw;
                    short8 a0 = wfp[abase + (size_t)tap * NC * 512];
                    short8 a1 = wfp[abase + (size_t)tap * NC * 512 + 64];
                    int toff = ((dd * 6 + dh) * 34 + dw) * 80;
                    short8 bb[4];
#pragma unroll
                    for (int j = 0; j < 4; ++j)
                        bb[j] = *(const short8*)(xs + bbase[j] + toff);
#pragma unroll
                    for (int j = 0; j < 4; ++j) {
                        acc[0][j] = __builtin_amdgcn_mfma_f32_16x16x32_bf16(a0, bb[j], acc[0][j], 0, 0, 0);
                        acc[1][j] = __builtin_amdgcn_mfma_f32_16x16x32_bf16(a1, bb[j], acc[1][j], 0, 0, 0);
                    }
                }
    }

    // epilogue: C/D mapping col=lane&15 (sp), row=(lane>>4)*4+q (co)
#pragma unroll
    for (int r = 0; r < 2; ++r) {
        int co = cog * 32 + r * 16 + kb * 4;
        float4 bv = *(const float4*)(bias + co);
#pragma unroll
        for (int j = 0; j < 4; ++j) {
            int sp = sg * 64 + j * 16 + lr;
            int p = d * 1024 + (hq * 4 + (sp >> 5)) * 32 + (sp & 31);
            ushort4 o;
            o.x = f2bu(acc[r][j][0] + bv.x);
            o.y = f2bu(acc[r][j][1] + bv.y);
            o.z = f2bu(acc[r][j][2] + bv.z);
            o.w = f2bu(acc[r][j][3] + bv.w);
            *(ushort4*)(y + ((size_t)b * R3 + p) * COUT + co) = o;
        }
    }
}

// ---------------- GN stats on channel-last bf16 ----------------
__global__ __launch_bounds__(256) void gn_stats_cl_k(const bf16* __restrict__ x,
                                                     float* __restrict__ gmean,
                                                     float* __restrict__ gistd) {
    int bg = blockIdx.x;
    int b = bg >> 3, g = bg & 7;
    const bf16* base = x + (size_t)b * R3 * COUT + g * 16;
    float s = 0.f, ss = 0.f;
    for (int e = threadIdx.x; e < R3 * 2; e += 256) {
        int p = e >> 1, h = e & 1;
        short8 v = *(const short8*)(base + (size_t)p * COUT + h * 8);
#pragma unroll
        for (int j = 0; j < 8; ++j) {
            float f = b2f((ushort)v[j]);
            s += f; ss = fmaf(f, f, ss);
        }
    }
    __shared__ float r1[256], r2[256];
    int t = threadIdx.x;
    r1[t] = s; r2[t] = ss; __syncthreads();
    for (int st = 128; st > 0; st >>= 1) {
        if (t < st) { r1[t] += r1[t + st]; r2[t] += r2[t + st]; }
        __syncthreads();
    }
    if (t == 0) {
        const float M = (float)(GSIZE * R3);
        float mean = r1[0] / M;
        float var = fmaxf(r2[0] / M - mean * mean, 0.f);
        gmean[bg] = mean;
        gistd[bg] = rsqrtf(var + 1e-5f);
    }
}

// ---------------- GN apply + swish on channel-last bf16 ----------------
__global__ __launch_bounds__(256) void gn_apply_cl_k(bf16* __restrict__ x,
                                                     const float* __restrict__ gmean,
                                                     const float* __restrict__ gistd,
                                                     const float* __restrict__ gamma,
                                                     const float* __restrict__ beta) {
    int u = blockIdx.x * 256 + threadIdx.x;  // (b, p, ci-octet): 8*32768*16
    int ci8 = u & 15;
    int p = (u >> 4) & (R3 - 1);
    int b = u >> 19;
    int ci = ci8 * 8;
    int bg = b * 8 + (ci8 >> 1);
    float mean = gmean[bg], istd = gistd[bg];
    bf16* ptr = x + ((size_t)b * R3 + p) * COUT + ci;
    short8 v = *(const short8*)ptr;
    ushort o[8];
#pragma unroll
    for (int j = 0; j < 8; ++j) {
        float f = b2f((ushort)v[j]);
        float yv = fmaf((f - mean) * istd, gamma[ci + j], beta[ci + j]);
        o[j] = f2bu(yv / (1.f + expf(-yv)));
    }
    *(short8*)ptr = *(short8*)o;
}

// ---------------- fp32 GN (point branch) ----------------
__global__ __launch_bounds__(1024) void gn_stats_k(const float* __restrict__ x,
                                                   float* __restrict__ gmean,
                                                   float* __restrict__ gistd, int S) {
    int bg = blockIdx.x;
    int t = threadIdx.x;
    const float* p = x + (size_t)bg * GSIZE * S;
    int M = GSIZE * S;
    float s = 0.f, ss = 0.f;
    for (int e = t; e < M; e += 1024) { float v = p[e]; s += v; ss = fmaf(v, v, ss); }
    __shared__ float r1[1024], r2[1024];
    r1[t] = s; r2[t] = ss; __syncthreads();
    for (int st = 512; st > 0; st >>= 1) {
        if (t < st) { r1[t] += r1[t + st]; r2[t] += r2[t + st]; }
        __syncthreads();
    }
    if (t == 0) {
        float mean = r1[0] / (float)M;
        float var = fmaxf(r2[0] / (float)M - mean * mean, 0.f);
        gmean[bg] = mean;
        gistd[bg] = rsqrtf(var + 1e-5f);
    }
}

__global__ __launch_bounds__(256) void gn_apply_swish_k(float* __restrict__ x,
                                                        const float* __restrict__ gmean,
                                                        const float* __restrict__ gistd,
                                                        const float* __restrict__ gamma,
                                                        const float* __restrict__ beta,
                                                        int logS) {
    unsigned int i = blockIdx.x * 256u + threadIdx.x;
    int c = (int)((i >> logS) & (COUT - 1));
    int bg = (int)(i >> (logS + 4));
    float v = x[i];
    float xn = (v - gmean[bg]) * gistd[bg];
    float yv = fmaf(xn, gamma[c], beta[c]);
    x[i] = yv / (1.f + expf(-yv));
}

// ---------------- point branch GEMM into d_out ----------------
__global__ __launch_bounds__(256) void point_gemm_k(const float* __restrict__ feats,
                                                    const float* __restrict__ wp,
                                                    const float* __restrict__ bp,
                                                    float* __restrict__ pf) {
    int blk = blockIdx.x;
    int b = blk / (NPTS / 256);
    int n = (blk % (NPTS / 256)) * 256 + threadIdx.x;
    float f[CIN];
    const float* fp = feats + ((size_t)b * CIN) * NPTS + n;
#pragma unroll
    for (int ci = 0; ci < CIN; ++ci) f[ci] = fp[(size_t)ci * NPTS];
    for (int c0 = 0; c0 < COUT; c0 += 8) {
        float a[8];
#pragma unroll
        for (int k = 0; k < 8; ++k) a[k] = bp[c0 + k];
#pragma unroll
        for (int ci = 0; ci < CIN; ++ci) {
            float fv = f[ci];
#pragma unroll
            for (int k = 0; k < 8; ++k) a[k] = fmaf(wp[(size_t)(c0 + k) * CIN + ci], fv, a[k]);
        }
        size_t ob = ((size_t)b * COUT + c0) * NPTS + n;
#pragma unroll
        for (int k = 0; k < 8; ++k) pf[ob + (size_t)k * NPTS] = a[k];
    }
}

// ---------------- trilinear devox (channel-last act2) + add ----------------
__global__ __launch_bounds__(256) void fuse_k(const bf16* __restrict__ vox,  // [b][p][128]
                                              const float* __restrict__ nc,
                                              float* __restrict__ out) {
    int g = blockIdx.x * 256 + threadIdx.x;
    int b = g / NPTS, n = g % NPTS;
    const float CMAX = (float)(RES - 1) - 1e-6f;
    float cx = fminf(nc[((size_t)b * 3 + 0) * NPTS + n], CMAX);
    float cy = fminf(nc[((size_t)b * 3 + 1) * NPTS + n], CMAX);
    float cz = fminf(nc[((size_t)b * 3 + 2) * NPTS + n], CMAX);
    int ix0 = (int)cx, iy0 = (int)cy, iz0 = (int)cz;
    float fx = cx - ix0, fy = cy - iy0, fz = cz - iz0;
    int ix1 = min(ix0 + 1, RES - 1), iy1 = min(iy0 + 1, RES - 1), iz1 = min(iz0 + 1, RES - 1);
    float gx0 = 1.f - fx, gy0 = 1.f - fy, gz0 = 1.f - fz;
    float wc[8] = {gx0 * gy0 * gz0, gx0 * gy0 * fz, gx0 * fy * gz0, gx0 * fy * fz,
                   fx * gy0 * gz0,  fx * gy0 * fz,  fx * fy * gz0,  fx * fy * fz};
    int fi[8];
    fi[0] = (ix0 * RES + iy0) * RES + iz0; fi[1] = (ix0 * RES + iy0) * RES + iz1;
    fi[2] = (ix0 * RES + iy1) * RES + iz0; fi[3] = (ix0 * RES + iy1) * RES + iz1;
    fi[4] = (ix1 * RES + iy0) * RES + iz0; fi[5] = (ix1 * RES + iy0) * RES + iz1;
    fi[6] = (ix1 * RES + iy1) * RES + iz0; fi[7] = (ix1 * RES + iy1) * RES + iz1;
    const bf16* vb = vox + (size_t)b * R3 * COUT;
    float* ob = out + ((size_t)b * COUT) * NPTS + n;
    for (int o = 0; o < COUT; o += 8) {
        float accv[8] = {0.f, 0.f, 0.f, 0.f, 0.f, 0.f, 0.f, 0.f};
#pragma unroll
        for (int f = 0; f < 8; ++f) {
            short8 v = *(const short8*)(vb + (size_t)fi[f] * COUT + o);
            float wgt = wc[f];
#pragma unroll
            for (int j = 0; j < 8; ++j) accv[j] = fmaf(wgt, b2f((ushort)v[j]), accv[j]);
        }
#pragma unroll
        for (int j = 0; j < 8; ++j) ob[(size_t)(o + j) * NPTS] += accv[j];
    }
}

extern "C" void kernel_launch(void* const* d_in, const int* in_sizes, int n_in,
                              void* d_out, int out_size, void* d_ws, size_t ws_size,
                              hipStream_t stream) {
    const float* features = (const float*)d_in[0];
    const float* coords   = (const float*)d_in[1];
    const float* w1  = (const float*)d_in[3];
    const float* b1  = (const float*)d_in[4];
    const float* g1g = (const float*)d_in[5];
    const float* g1b = (const float*)d_in[6];
    const float* w2  = (const float*)d_in[7];
    const float* b2  = (const float*)d_in[8];
    const float* g2g = (const float*)d_in[9];
    const float* g2b = (const float*)d_in[10];
    const float* wp  = (const float*)d_in[11];
    const float* bp  = (const float*)d_in[12];
    const float* gpg = (const float*)d_in[13];
    const float* gpb = (const float*)d_in[14];
    float* out = (float*)d_out;

    // ws layout (~164 MB):
    //   [0,64MB)      sums fp32 [b][p][64]  -> later act2 bf16 [b][p][128] (overlay)
    //   [64,96MB)     voxCL bf16 [b][p][64]
    //   [96,160MB)    act1 bf16 [b][p][128]
    //   then w1f (442KB), w2f (884KB), nc (1.5MB), cnts (1MB), stats
    char* ws = (char*)d_ws;
    size_t off = 0;
    float* sums = (float*)(ws + off);
    bf16* act2 = (bf16*)(ws + off);          off += (size_t)BATCH * R3 * CIN * 4;   // 64MB
    bf16* voxCL = (bf16*)(ws + off);         off += (size_t)BATCH * R3 * CIN * 2;   // 32MB
    bf16* act1 = (bf16*)(ws + off);          off += (size_t)BATCH * R3 * COUT * 2;  // 64MB
    bf16* w1f = (bf16*)(ws + off);           off += (size_t)27 * 2 * 128 * 32 * 2;
    bf16* w2f = (bf16*)(ws + off);           off += (size_t)27 * 4 * 128 * 32 * 2;
    float* ncb = (float*)(ws + off);         off += (size_t)BATCH * 3 * NPTS * 4;
    float* cnts = (float*)(ws + off);        off += (size_t)BATCH * R3 * 4;
    float* bstats = (float*)(ws + off);      off += 256;
    float* gmean = (float*)(ws + off);       off += 256;
    float* gistd = (float*)(ws + off);       off += 256;

    hipMemsetAsync(sums, 0, (size_t)BATCH * R3 * CIN * 4, stream);
    hipMemsetAsync(cnts, 0, (size_t)BATCH * R3 * 4, stream);

    coord_stats_k<<<BATCH, 256, 0, stream>>>(coords, bstats);
    voxelize_k<<<BATCH * NPTS / 256, 256, 0, stream>>>(coords, features, bstats, ncb, sums, cnts);
    finalize_convert_k<<<BATCH * R3 * 8 / 256, 256, 0, stream>>>(sums, cnts, voxCL);

    wreorder_k<CIN><<<(27 * 2 * 128 * 4 + 255) / 256, 256, 0, stream>>>(w1, w1f);
    wreorder_k<COUT><<<(27 * 4 * 128 * 4 + 255) / 256, 256, 0, stream>>>(w2, w2f);

    conv3d_mfma_k<CIN><<<BATCH * 32 * 8, 512, 0, stream>>>(voxCL, w1f, b1, act1);
    gn_stats_cl_k<<<BATCH * NGROUP, 256, 0, stream>>>(act1, gmean, gistd);
    gn_apply_cl_k<<<BATCH * R3 * 16 / 256, 256, 0, stream>>>(act1, gmean, gistd, g1g, g1b);

    conv3d_mfma_k<COUT><<<BATCH * 32 * 8, 512, 0, stream>>>(act1, w2f, b2, act2);
    gn_stats_cl_k<<<BATCH * NGROUP, 256, 0, stream>>>(act2, gmean, gistd);
    gn_apply_cl_k<<<BATCH * R3 * 16 / 256, 256, 0, stream>>>(act2, gmean, gistd, g2g, g2b);

    point_gemm_k<<<BATCH * NPTS / 256, 256, 0, stream>>>(features, wp, bp, out);
    gn_stats_k<<<BATCH * NGROUP, 1024, 0, stream>>>(out, gmean, gistd, NPTS);
    gn_apply_swish_k<<<BATCH * COUT * NPTS / 256, 256, 0, stream>>>(out, gmean, gistd, gpg, gpb, 14);

    fuse_k<<<BATCH * NPTS / 256, 256, 0, stream>>>(act2, ncb, out);
}

// Round 4
// 956.217 us; speedup vs baseline: 11.4761x; 1.5146x over previous
//
#include <hip/hip_runtime.h>
#include <hip/hip_bf16.h>
#include <cmath>

#define BATCH 8
#define CIN 64
#define COUT 128
#define NPTS 16384
#define RES 32
#define R3 32768
#define NGROUP 8
#define GSIZE 16

typedef __hip_bfloat16 bf16;
typedef __attribute__((ext_vector_type(8))) short short8;
typedef __attribute__((ext_vector_type(4))) float f32x4;

__device__ inline float b2f(ushort u) { union { float f; uint v; } x; x.v = ((uint)u) << 16; return x.f; }
__device__ inline ushort f2bu(float f) { __hip_bfloat16 h = __float2bfloat16(f); return *reinterpret_cast<ushort*>(&h); }

// ---------------- coord stats ----------------
__global__ __launch_bounds__(256) void coord_stats_k(const float* __restrict__ coords,
                                                     float* __restrict__ bstats) {
    int b = blockIdx.x;
    int t = threadIdx.x;
    __shared__ float red[256];
    __shared__ float means[3];
    for (int c = 0; c < 3; ++c) {
        float acc = 0.f;
        const float* p = coords + ((size_t)b * 3 + c) * NPTS;
        for (int n = t; n < NPTS; n += 256) acc += p[n];
        red[t] = acc; __syncthreads();
        for (int s = 128; s > 0; s >>= 1) { if (t < s) red[t] += red[t + s]; __syncthreads(); }
        if (t == 0) means[c] = red[0] * (1.f / NPTS);
        __syncthreads();
    }
    float m0 = means[0], m1 = means[1], m2 = means[2];
    const float* px = coords + ((size_t)b * 3 + 0) * NPTS;
    const float* py = coords + ((size_t)b * 3 + 1) * NPTS;
    const float* pz = coords + ((size_t)b * 3 + 2) * NPTS;
    float mx = 0.f;
    for (int n = t; n < NPTS; n += 256) {
        float dx = px[n] - m0, dy = py[n] - m1, dz = pz[n] - m2;
        mx = fmaxf(mx, sqrtf(dx * dx + dy * dy + dz * dz));
    }
    red[t] = mx; __syncthreads();
    for (int s = 128; s > 0; s >>= 1) { if (t < s) red[t] = fmaxf(red[t], red[t + s]); __syncthreads(); }
    if (t == 0) {
        bstats[b * 4 + 0] = m0; bstats[b * 4 + 1] = m1; bstats[b * 4 + 2] = m2;
        bstats[b * 4 + 3] = 1.f / (2.f * red[0]);
    }
}

// ---------------- per-point voxel index + nc + count ----------------
__global__ __launch_bounds__(256) void vox_idx_k(const float* __restrict__ coords,
                                                 const float* __restrict__ bstats,
                                                 float* __restrict__ nc,
                                                 int* __restrict__ vidx,
                                                 int* __restrict__ slot,
                                                 unsigned int* __restrict__ cnts) {
    int g = blockIdx.x * 256 + threadIdx.x;
    int b = g >> 14, n = g & (NPTS - 1);
    float m0 = bstats[b * 4 + 0], m1 = bstats[b * 4 + 1], m2 = bstats[b * 4 + 2];
    float sc = bstats[b * 4 + 3];
    float x = coords[((size_t)b * 3 + 0) * NPTS + n];
    float y = coords[((size_t)b * 3 + 1) * NPTS + n];
    float z = coords[((size_t)b * 3 + 2) * NPTS + n];
    float ncx = fminf(fmaxf(((x - m0) * sc + 0.5f) * (float)RES, 0.f), RES - 1.f);
    float ncy = fminf(fmaxf(((y - m1) * sc + 0.5f) * (float)RES, 0.f), RES - 1.f);
    float ncz = fminf(fmaxf(((z - m2) * sc + 0.5f) * (float)RES, 0.f), RES - 1.f);
    nc[((size_t)b * 3 + 0) * NPTS + n] = ncx;
    nc[((size_t)b * 3 + 1) * NPTS + n] = ncy;
    nc[((size_t)b * 3 + 2) * NPTS + n] = ncz;
    int ix = min(max((int)rintf(ncx), 0), RES - 1);  // rintf = half-even = jnp.round
    int iy = min(max((int)rintf(ncy), 0), RES - 1);
    int iz = min(max((int)rintf(ncz), 0), RES - 1);
    int v = b * R3 + (ix * RES + iy) * RES + iz;
    vidx[g] = v;
    slot[g] = (int)atomicAdd(&cnts[v], 1u);
}

// ---------------- feature transpose: [b][64][N] fp32 -> [b][n][64] fp32 ----------------
__global__ __launch_bounds__(256) void transpose_feats_k(const float* __restrict__ feats,
                                                         float* __restrict__ featT) {
    int blk = blockIdx.x;        // b*256 + ntile
    int b = blk >> 8, ntile = blk & 255;
    int t = threadIdx.x;
    __shared__ float lds[64][65];
    for (int e = t; e < 64 * 64; e += 256) {
        int c = e >> 6, n = e & 63;
        lds[c][n] = feats[((size_t)b * CIN + c) * NPTS + ntile * 64 + n];
    }
    __syncthreads();
    for (int e = t; e < 64 * 64; e += 256) {
        int n = e >> 6, c = e & 63;
        featT[(((size_t)b << 14) + ntile * 64 + n) * CIN + c] = lds[c][n];
    }
}

// ---------------- scan: exclusive prefix over 262144 counts ----------------
__global__ __launch_bounds__(256) void scan1_k(const unsigned int* __restrict__ cnts,
                                               unsigned int* __restrict__ offs,
                                               unsigned int* __restrict__ part) {
    int t = threadIdx.x;
    int g = blockIdx.x * 256 + t;
    unsigned int v = cnts[g];
    __shared__ unsigned int s[256];
    s[t] = v; __syncthreads();
    for (int d = 1; d < 256; d <<= 1) {
        unsigned int x = (t >= d) ? s[t - d] : 0u;
        __syncthreads();
        s[t] += x;
        __syncthreads();
    }
    offs[g] = s[t] - v;
    if (t == 255) part[blockIdx.x] = s[255];
}

__global__ __launch_bounds__(1024) void scan2_k(unsigned int* __restrict__ part) {
    int t = threadIdx.x;
    unsigned int v = part[t];
    __shared__ unsigned int s[1024];
    s[t] = v; __syncthreads();
    for (int d = 1; d < 1024; d <<= 1) {
        unsigned int x = (t >= d) ? s[t - d] : 0u;
        __syncthreads();
        s[t] += x;
        __syncthreads();
    }
    part[t] = s[t] - v;  // exclusive
}

__global__ __launch_bounds__(256) void scan3_k(unsigned int* __restrict__ offs,
                                               const unsigned int* __restrict__ part) {
    int g = blockIdx.x * 256 + threadIdx.x;
    offs[g] += part[blockIdx.x];
}

// ---------------- scatter point ids into CSR lists ----------------
__global__ __launch_bounds__(256) void scatter_pts_k(const int* __restrict__ vidx,
                                                     const int* __restrict__ slot,
                                                     const unsigned int* __restrict__ offs,
                                                     unsigned int* __restrict__ pidx) {
    int g = blockIdx.x * 256 + threadIdx.x;
    int n = g & (NPTS - 1);
    int v = vidx[g];
    pidx[offs[v] + slot[g]] = (unsigned int)n;
}

// ---------------- gather: CSR mean -> bf16 channel-last vox ----------------
__global__ __launch_bounds__(256) void gather_k(const float* __restrict__ featT,
                                                const unsigned int* __restrict__ cnts,
                                                const unsigned int* __restrict__ offs,
                                                const unsigned int* __restrict__ pidx,
                                                bf16* __restrict__ voxCL) {
    int u = blockIdx.x * 256 + threadIdx.x;  // (voxel, lane8): 262144*8
    int v = u >> 3;
    int l8 = u & 7;
    int b = v >> 15;
    unsigned int cnt = cnts[v];
    unsigned int off = offs[v];
    float acc[8] = {0.f, 0.f, 0.f, 0.f, 0.f, 0.f, 0.f, 0.f};
    for (unsigned int i = 0; i < cnt; ++i) {
        unsigned int n = pidx[off + i];
        const float4* fp = (const float4*)(featT + (((size_t)b << 14) + n) * CIN + l8 * 8);
        float4 f0 = fp[0], f1 = fp[1];
        acc[0] += f0.x; acc[1] += f0.y; acc[2] += f0.z; acc[3] += f0.w;
        acc[4] += f1.x; acc[5] += f1.y; acc[6] += f1.z; acc[7] += f1.w;
    }
    float inv = 1.f / fmaxf((float)cnt, 1.f);
    ushort o[8];
#pragma unroll
    for (int j = 0; j < 8; ++j) o[j] = f2bu(acc[j] * inv);
    *(short8*)(voxCL + (size_t)v * CIN + l8 * 8) = *(short8*)o;
}

// ---------------- weight reorder: [co][ci][27] fp32 -> [t][c32][co][kb][8] bf16 ----------------
template <int CIN_T>
__global__ __launch_bounds__(256) void wreorder_k(const float* __restrict__ w,
                                                  bf16* __restrict__ wf) {
    const int NC = CIN_T / 32;
    int u = blockIdx.x * 256 + threadIdx.x;
    if (u >= 27 * NC * 128 * 4) return;
    int kb = u & 3;
    int co = (u >> 2) & 127;
    int c32 = (u >> 9) % NC;
    int t = u / (512 * NC);
    int cibase = c32 * 32 + kb * 8;
    ushort o[8];
#pragma unroll
    for (int j = 0; j < 8; ++j)
        o[j] = f2bu(w[((size_t)co * CIN_T + cibase + j) * 27 + t]);
    *(short8*)(wf + (size_t)u * 8) = *(short8*)o;
}

// ---------------- implicit-GEMM conv3d 3x3x3 via MFMA bf16 ----------------
template <int CIN_T>
__global__ __launch_bounds__(512, 2) void conv3d_mfma_k(const bf16* __restrict__ x,  // [b][p][CIN_T]
                                                        const bf16* __restrict__ wf, // [27][NC][128][4][8]
                                                        const float* __restrict__ bias,
                                                        bf16* __restrict__ y) {      // [b][p][128]
    constexpr int NC = CIN_T / 32;
    int blk = blockIdx.x;
    int hq = blk & 7;
    int d = (blk >> 3) & 31;
    int b = blk >> 8;
    int t = threadIdx.x;
    int lane = t & 63;
    int wid = t >> 6;
    int cog = wid >> 1;
    int sg = wid & 1;
    int lr = lane & 15;
    int kb = lane >> 4;

    __shared__ __align__(16) char xs[3 * 6 * 34 * 80];

    f32x4 acc[2][4];
#pragma unroll
    for (int r = 0; r < 2; ++r)
#pragma unroll
        for (int j = 0; j < 4; ++j) acc[r][j] = (f32x4){0.f, 0.f, 0.f, 0.f};

    int bbase[4];
#pragma unroll
    for (int j = 0; j < 4; ++j) {
        int sp = sg * 64 + j * 16 + lr;
        int hl = sp >> 5, wl = sp & 31;
        bbase[j] = (hl * 34 + wl) * 80 + kb * 16;
    }

    for (int cc = 0; cc < NC; ++cc) {
        __syncthreads();
        for (int e = t; e < 612 * 4; e += 512) {
            int ekb = e & 3;
            int pos = e >> 2;
            int ww = pos % 34;
            int hh = (pos / 34) % 6;
            int dd = pos / 204;
            int dz = d + dd - 1;
            int hz = hq * 4 + hh - 1;
            int wz = ww - 1;
            short8 v = {0, 0, 0, 0, 0, 0, 0, 0};
            if (dz >= 0 && dz < RES && hz >= 0 && hz < RES && wz >= 0 && wz < RES)
                v = *(const short8*)(x + ((size_t)b * R3 + dz * 1024 + hz * 32 + wz) * CIN_T + cc * 32 + ekb * 8);
            *(short8*)(xs + pos * 80 + ekb * 16) = v;
        }
        __syncthreads();

        const short8* wfp = (const short8*)wf;
        size_t abase = ((size_t)cc * 128 + cog * 32 + lr) * 4 + kb;
#pragma unroll
        for (int dd = 0; dd < 3; ++dd)
#pragma unroll
            for (int dh = 0; dh < 3; ++dh)
#pragma unroll
                for (int dw = 0; dw < 3; ++dw) {
                    int tap = (dd * 3 + dh) * 3 + dw;
                    short8 a0 = wfp[abase + (size_t)tap * NC * 512];
                    short8 a1 = wfp[abase + (size_t)tap * NC * 512 + 64];
                    int toff = ((dd * 6 + dh) * 34 + dw) * 80;
                    short8 bb[4];
#pragma unroll
                    for (int j = 0; j < 4; ++j)
                        bb[j] = *(const short8*)(xs + bbase[j] + toff);
#pragma unroll
                    for (int j = 0; j < 4; ++j) {
                        acc[0][j] = __builtin_amdgcn_mfma_f32_16x16x32_bf16(a0, bb[j], acc[0][j], 0, 0, 0);
                        acc[1][j] = __builtin_amdgcn_mfma_f32_16x16x32_bf16(a1, bb[j], acc[1][j], 0, 0, 0);
                    }
                }
    }

#pragma unroll
    for (int r = 0; r < 2; ++r) {
        int co = cog * 32 + r * 16 + kb * 4;
        float4 bv = *(const float4*)(bias + co);
#pragma unroll
        for (int j = 0; j < 4; ++j) {
            int sp = sg * 64 + j * 16 + lr;
            int p = d * 1024 + (hq * 4 + (sp >> 5)) * 32 + (sp & 31);
            ushort4 o;
            o.x = f2bu(acc[r][j][0] + bv.x);
            o.y = f2bu(acc[r][j][1] + bv.y);
            o.z = f2bu(acc[r][j][2] + bv.z);
            o.w = f2bu(acc[r][j][3] + bv.w);
            *(ushort4*)(y + ((size_t)b * R3 + p) * COUT + co) = o;
        }
    }
}

// ---------------- GN stats on channel-last bf16 ----------------
__global__ __launch_bounds__(256) void gn_stats_cl_k(const bf16* __restrict__ x,
                                                     float* __restrict__ gmean,
                                                     float* __restrict__ gistd) {
    int bg = blockIdx.x;
    int b = bg >> 3, g = bg & 7;
    const bf16* base = x + (size_t)b * R3 * COUT + g * 16;
    float s = 0.f, ss = 0.f;
    for (int e = threadIdx.x; e < R3 * 2; e += 256) {
        int p = e >> 1, h = e & 1;
        short8 v = *(const short8*)(base + (size_t)p * COUT + h * 8);
#pragma unroll
        for (int j = 0; j < 8; ++j) {
            float f = b2f((ushort)v[j]);
            s += f; ss = fmaf(f, f, ss);
        }
    }
    __shared__ float r1[256], r2[256];
    int t = threadIdx.x;
    r1[t] = s; r2[t] = ss; __syncthreads();
    for (int st = 128; st > 0; st >>= 1) {
        if (t < st) { r1[t] += r1[t + st]; r2[t] += r2[t + st]; }
        __syncthreads();
    }
    if (t == 0) {
        const float M = (float)(GSIZE * R3);
        float mean = r1[0] / M;
        float var = fmaxf(r2[0] / M - mean * mean, 0.f);
        gmean[bg] = mean;
        gistd[bg] = rsqrtf(var + 1e-5f);
    }
}

// ---------------- GN apply + swish on channel-last bf16 ----------------
__global__ __launch_bounds__(256) void gn_apply_cl_k(bf16* __restrict__ x,
                                                     const float* __restrict__ gmean,
                                                     const float* __restrict__ gistd,
                                                     const float* __restrict__ gamma,
                                                     const float* __restrict__ beta) {
    int u = blockIdx.x * 256 + threadIdx.x;
    int ci8 = u & 15;
    int p = (u >> 4) & (R3 - 1);
    int b = u >> 19;
    int ci = ci8 * 8;
    int bg = b * 8 + (ci8 >> 1);
    float mean = gmean[bg], istd = gistd[bg];
    bf16* ptr = x + ((size_t)b * R3 + p) * COUT + ci;
    short8 v = *(const short8*)ptr;
    ushort o[8];
#pragma unroll
    for (int j = 0; j < 8; ++j) {
        float f = b2f((ushort)v[j]);
        float yv = fmaf((f - mean) * istd, gamma[ci + j], beta[ci + j]);
        o[j] = f2bu(yv / (1.f + expf(-yv)));
    }
    *(short8*)ptr = *(short8*)o;
}

// ---------------- fp32 GN stats (point branch) ----------------
__global__ __launch_bounds__(1024) void gn_stats_k(const float* __restrict__ x,
                                                   float* __restrict__ gmean,
                                                   float* __restrict__ gistd, int S) {
    int bg = blockIdx.x;
    int t = threadIdx.x;
    const float* p = x + (size_t)bg * GSIZE * S;
    int M = GSIZE * S;
    float s = 0.f, ss = 0.f;
    for (int e = t; e < M; e += 1024) { float v = p[e]; s += v; ss = fmaf(v, v, ss); }
    __shared__ float r1[1024], r2[1024];
    r1[t] = s; r2[t] = ss; __syncthreads();
    for (int st = 512; st > 0; st >>= 1) {
        if (t < st) { r1[t] += r1[t + st]; r2[t] += r2[t + st]; }
        __syncthreads();
    }
    if (t == 0) {
        float mean = r1[0] / (float)M;
        float var = fmaxf(r2[0] / (float)M - mean * mean, 0.f);
        gmean[bg] = mean;
        gistd[bg] = rsqrtf(var + 1e-5f);
    }
}

// ---------------- point branch GEMM into d_out ----------------
__global__ __launch_bounds__(256) void point_gemm_k(const float* __restrict__ feats,
                                                    const float* __restrict__ wp,
                                                    const float* __restrict__ bp,
                                                    float* __restrict__ pf) {
    int blk = blockIdx.x;
    int b = blk / (NPTS / 256);
    int n = (blk % (NPTS / 256)) * 256 + threadIdx.x;
    float f[CIN];
    const float* fp = feats + ((size_t)b * CIN) * NPTS + n;
#pragma unroll
    for (int ci = 0; ci < CIN; ++ci) f[ci] = fp[(size_t)ci * NPTS];
    for (int c0 = 0; c0 < COUT; c0 += 8) {
        float a[8];
#pragma unroll
        for (int k = 0; k < 8; ++k) a[k] = bp[c0 + k];
#pragma unroll
        for (int ci = 0; ci < CIN; ++ci) {
            float fv = f[ci];
#pragma unroll
            for (int k = 0; k < 8; ++k) a[k] = fmaf(wp[(size_t)(c0 + k) * CIN + ci], fv, a[k]);
        }
        size_t ob = ((size_t)b * COUT + c0) * NPTS + n;
#pragma unroll
        for (int k = 0; k < 8; ++k) pf[ob + (size_t)k * NPTS] = a[k];
    }
}

// ---------------- trilinear devox + point-branch GN/swish + add ----------------
__global__ __launch_bounds__(256) void fuse_k(const bf16* __restrict__ vox,  // [b][p][128]
                                              const float* __restrict__ nc,
                                              const float* __restrict__ gmean,
                                              const float* __restrict__ gistd,
                                              const float* __restrict__ gpg,
                                              const float* __restrict__ gpb,
                                              float* __restrict__ out) {
    int g = blockIdx.x * 256 + threadIdx.x;
    int b = g / NPTS, n = g % NPTS;
    const float CMAX = (float)(RES - 1) - 1e-6f;
    float cx = fminf(nc[((size_t)b * 3 + 0) * NPTS + n], CMAX);
    float cy = fminf(nc[((size_t)b * 3 + 1) * NPTS + n], CMAX);
    float cz = fminf(nc[((size_t)b * 3 + 2) * NPTS + n], CMAX);
    int ix0 = (int)cx, iy0 = (int)cy, iz0 = (int)cz;
    float fx = cx - ix0, fy = cy - iy0, fz = cz - iz0;
    int ix1 = min(ix0 + 1, RES - 1), iy1 = min(iy0 + 1, RES - 1), iz1 = min(iz0 + 1, RES - 1);
    float gx0 = 1.f - fx, gy0 = 1.f - fy, gz0 = 1.f - fz;
    float wc[8] = {gx0 * gy0 * gz0, gx0 * gy0 * fz, gx0 * fy * gz0, gx0 * fy * fz,
                   fx * gy0 * gz0,  fx * gy0 * fz,  fx * fy * gz0,  fx * fy * fz};
    int fi[8];
    fi[0] = (ix0 * RES + iy0) * RES + iz0; fi[1] = (ix0 * RES + iy0) * RES + iz1;
    fi[2] = (ix0 * RES + iy1) * RES + iz0; fi[3] = (ix0 * RES + iy1) * RES + iz1;
    fi[4] = (ix1 * RES + iy0) * RES + iz0; fi[5] = (ix1 * RES + iy0) * RES + iz1;
    fi[6] = (ix1 * RES + iy1) * RES + iz0; fi[7] = (ix1 * RES + iy1) * RES + iz1;
    const bf16* vb = vox + (size_t)b * R3 * COUT;
    float* ob = out + ((size_t)b * COUT) * NPTS + n;
    for (int o = 0; o < COUT; o += 8) {
        float accv[8] = {0.f, 0.f, 0.f, 0.f, 0.f, 0.f, 0.f, 0.f};
#pragma unroll
        for (int f = 0; f < 8; ++f) {
            short8 v = *(const short8*)(vb + (size_t)fi[f] * COUT + o);
            float wgt = wc[f];
#pragma unroll
            for (int j = 0; j < 8; ++j) accv[j] = fmaf(wgt, b2f((ushort)v[j]), accv[j]);
        }
        int bgp = b * 8 + (o >> 4);
        float mean = gmean[bgp], istd = gistd[bgp];
#pragma unroll
        for (int j = 0; j < 8; ++j) {
            float pf = ob[(size_t)(o + j) * NPTS];
            float yv = fmaf((pf - mean) * istd, gpg[o + j], gpb[o + j]);
            float sw = yv / (1.f + expf(-yv));
            ob[(size_t)(o + j) * NPTS] = sw + accv[j];
        }
    }
}

extern "C" void kernel_launch(void* const* d_in, const int* in_sizes, int n_in,
                              void* d_out, int out_size, void* d_ws, size_t ws_size,
                              hipStream_t stream) {
    const float* features = (const float*)d_in[0];
    const float* coords   = (const float*)d_in[1];
    const float* w1  = (const float*)d_in[3];
    const float* b1  = (const float*)d_in[4];
    const float* g1g = (const float*)d_in[5];
    const float* g1b = (const float*)d_in[6];
    const float* w2  = (const float*)d_in[7];
    const float* b2  = (const float*)d_in[8];
    const float* g2g = (const float*)d_in[9];
    const float* g2b = (const float*)d_in[10];
    const float* wp  = (const float*)d_in[11];
    const float* bp  = (const float*)d_in[12];
    const float* gpg = (const float*)d_in[13];
    const float* gpb = (const float*)d_in[14];
    float* out = (float*)d_out;

    // ws layout (~135 MB):
    //   [0,64MB)    act1 bf16 [b][p][128]
    //   [64,128MB)  region R: voxCL bf16 32MB | featT fp32 32MB  -> act2 bf16 overlays all 64MB
    //   tail: w1f, w2f, nc, cnts, offs, vidx, slot, pidx, part, bstats, gmean, gistd
    char* ws = (char*)d_ws;
    size_t off = 0;
    bf16* act1 = (bf16*)(ws + off);          off += (size_t)BATCH * R3 * COUT * 2;  // 64MB
    bf16* act2 = (bf16*)(ws + off);          // overlays voxCL+featT
    bf16* voxCL = (bf16*)(ws + off);         off += (size_t)BATCH * R3 * CIN * 2;   // 32MB
    float* featT = (float*)(ws + off);       off += (size_t)BATCH * NPTS * CIN * 4; // 32MB
    bf16* w1f = (bf16*)(ws + off);           off += (size_t)27 * 2 * 128 * 32 * 2;
    bf16* w2f = (bf16*)(ws + off);           off += (size_t)27 * 4 * 128 * 32 * 2;
    float* ncb = (float*)(ws + off);         off += (size_t)BATCH * 3 * NPTS * 4;
    unsigned int* cnts = (unsigned int*)(ws + off);  off += (size_t)BATCH * R3 * 4;
    unsigned int* offs = (unsigned int*)(ws + off);  off += (size_t)BATCH * R3 * 4;
    int* vidx = (int*)(ws + off);            off += (size_t)BATCH * NPTS * 4;
    int* slot = (int*)(ws + off);            off += (size_t)BATCH * NPTS * 4;
    unsigned int* pidx = (unsigned int*)(ws + off);  off += (size_t)BATCH * NPTS * 4;
    unsigned int* part = (unsigned int*)(ws + off);  off += 4096;
    float* bstats = (float*)(ws + off);      off += 256;
    float* gmean = (float*)(ws + off);       off += 256;
    float* gistd = (float*)(ws + off);       off += 256;

    hipMemsetAsync(cnts, 0, (size_t)BATCH * R3 * 4, stream);

    coord_stats_k<<<BATCH, 256, 0, stream>>>(coords, bstats);
    vox_idx_k<<<BATCH * NPTS / 256, 256, 0, stream>>>(coords, bstats, ncb, vidx, slot, cnts);
    transpose_feats_k<<<BATCH * 256, 256, 0, stream>>>(features, featT);
    scan1_k<<<BATCH * R3 / 256, 256, 0, stream>>>(cnts, offs, part);
    scan2_k<<<1, 1024, 0, stream>>>(part);
    scan3_k<<<BATCH * R3 / 256, 256, 0, stream>>>(offs, part);
    scatter_pts_k<<<BATCH * NPTS / 256, 256, 0, stream>>>(vidx, slot, offs, pidx);
    gather_k<<<BATCH * R3 * 8 / 256, 256, 0, stream>>>(featT, cnts, offs, pidx, voxCL);

    wreorder_k<CIN><<<(27 * 2 * 128 * 4 + 255) / 256, 256, 0, stream>>>(w1, w1f);
    wreorder_k<COUT><<<(27 * 4 * 128 * 4 + 255) / 256, 256, 0, stream>>>(w2, w2f);

    conv3d_mfma_k<CIN><<<BATCH * 32 * 8, 512, 0, stream>>>(voxCL, w1f, b1, act1);
    gn_stats_cl_k<<<BATCH * NGROUP, 256, 0, stream>>>(act1, gmean, gistd);
    gn_apply_cl_k<<<BATCH * R3 * 16 / 256, 256, 0, stream>>>(act1, gmean, gistd, g1g, g1b);

    conv3d_mfma_k<COUT><<<BATCH * 32 * 8, 512, 0, stream>>>(act1, w2f, b2, act2);
    gn_stats_cl_k<<<BATCH * NGROUP, 256, 0, stream>>>(act2, gmean, gistd);
    gn_apply_cl_k<<<BATCH * R3 * 16 / 256, 256, 0, stream>>>(act2, gmean, gistd, g2g, g2b);

    point_gemm_k<<<BATCH * NPTS / 256, 256, 0, stream>>>(features, wp, bp, out);
    gn_stats_k<<<BATCH * NGROUP, 1024, 0, stream>>>(out, gmean, gistd, NPTS);

    fuse_k<<<BATCH * NPTS / 256, 256, 0, stream>>>(act2, ncb, gmean, gistd, gpg, gpb, out);
}